// Round 1
// baseline (22.853 us; speedup 1.0000x reference)
//
#include <hip/hip_runtime.h>

// RBF network fused kernel, fp32 vector path.
// inputs:  x[B=2048][F=128], centers c[H=512][F=128], sigma[1], W[O=10][H=512], b[O=10]
// out[b][o] = sum_h exp(-||x_b - c_h||^2 / (2 sigma^2)) * W[o][h] + b[o]

constexpr int Fdim = 128;
constexpr int Hdim = 512;
constexpr int Odim = 10;
constexpr int BM   = 32;    // rows per block
constexpr int BH   = 128;   // centers per block
constexpr int KC   = 64;    // F chunk staged in LDS

__global__ __launch_bounds__(256, 2) void rbf_fused(
    const float* __restrict__ x,
    const float* __restrict__ c,
    const float* __restrict__ sigmap,
    const float* __restrict__ W,
    const float* __restrict__ bias,
    float* __restrict__ out)
{
    // cT[f][h] transposed + XOR col4 swizzle -> conflict-free b128 reads in main loop
    __shared__ float cT[KC][BH];           // 32 KiB
    __shared__ float xT[KC][36];           // 9 KiB  (pad 32->36 keeps b128 aligned)
    __shared__ float rbf_s[BM][BH + 4];    // 16.9 KiB
    __shared__ float W_s[Odim][BH];        // 5 KiB          total ~63 KiB

    const int tid  = threadIdx.x;
    const int row0 = blockIdx.x * BM;
    const int h0   = blockIdx.y * BH;

    // ---- stage W tile (once): W[o][h0..h0+127]
#pragma unroll
    for (int k = 0; k < (Odim * BH) / 256; ++k) {   // 1280/256 = 5
        int idx = tid + 256 * k;
        int o   = idx >> 7;
        int hh  = idx & 127;
        W_s[o][hh] = W[o * Hdim + h0 + hh];
    }

    const int tr = tid >> 5;   // 0..7  -> rows 4*tr..4*tr+3
    const int tc = tid & 31;   // 0..31 -> h    4*tc..4*tc+3

    float acc[4][4] = {};

    for (int fc = 0; fc < Fdim; fc += KC) {
        // ---- stage x chunk: xT[floc][r] = x[row0+r][fc+floc]
#pragma unroll
        for (int p = 0; p < (BM * KC / 4) / 256; ++p) {   // 2
            int idx = tid + 256 * p;
            int f4  = idx & 15;     // KC/4 = 16 float4 per row
            int r   = idx >> 4;     // 0..31
            float4 v = reinterpret_cast<const float4*>(x)[(size_t)(row0 + r) * (Fdim / 4) + fc / 4 + f4];
            xT[4 * f4 + 0][r] = v.x;
            xT[4 * f4 + 1][r] = v.y;
            xT[4 * f4 + 2][r] = v.z;
            xT[4 * f4 + 3][r] = v.w;
        }
        // ---- stage c chunk with in-register 4x4 transpose:
        // cT[floc][(hq ^ (floc&7))*4 + i] = c[h0+4*hq+i][fc+floc]
#pragma unroll
        for (int p = 0; p < (BH * KC / 16) / 256; ++p) {  // 2
            int bid = tid + 256 * p;
            int fq  = bid & 15;     // f-quad
            int hq  = bid >> 4;     // 0..31 h-quad
            const float4* cp = reinterpret_cast<const float4*>(c);
            size_t base = (size_t)(h0 + 4 * hq) * (Fdim / 4) + fc / 4 + fq;
            float4 v0 = cp[base];
            float4 v1 = cp[base + (Fdim / 4)];
            float4 v2 = cp[base + 2 * (Fdim / 4)];
            float4 v3 = cp[base + 3 * (Fdim / 4)];
            float a0[4] = {v0.x, v0.y, v0.z, v0.w};
            float a1[4] = {v1.x, v1.y, v1.z, v1.w};
            float a2[4] = {v2.x, v2.y, v2.z, v2.w};
            float a3[4] = {v3.x, v3.y, v3.z, v3.w};
#pragma unroll
            for (int j = 0; j < 4; ++j) {
                int row  = 4 * fq + j;
                int col4 = hq ^ (row & 7);
                float4 w4;
                w4.x = a0[j]; w4.y = a1[j]; w4.z = a2[j]; w4.w = a3[j];
                *reinterpret_cast<float4*>(&cT[row][col4 * 4]) = w4;
            }
        }
        __syncthreads();

        // ---- main compute: 4x4 micro-tile, diff-form
#pragma unroll 8
        for (int f = 0; f < KC; ++f) {
            float4 xv = *reinterpret_cast<const float4*>(&xT[f][4 * tr]);
            int    c4 = tc ^ (f & 7);
            float4 cv = *reinterpret_cast<const float4*>(&cT[f][c4 * 4]);
            float xr[4] = {xv.x, xv.y, xv.z, xv.w};
            float cc[4] = {cv.x, cv.y, cv.z, cv.w};
#pragma unroll
            for (int i = 0; i < 4; ++i)
#pragma unroll
                for (int j = 0; j < 4; ++j) {
                    float d = xr[i] - cc[j];
                    acc[i][j] = fmaf(d, d, acc[i][j]);
                }
        }
        __syncthreads();
    }

    // ---- rbf = exp(-dist/(2 sigma^2)) -> LDS
    const float sg    = sigmap[0];
    const float scale = -1.0f / (2.0f * sg * sg);
#pragma unroll
    for (int i = 0; i < 4; ++i) {
        float4 rv;
        rv.x = __expf(acc[i][0] * scale);
        rv.y = __expf(acc[i][1] * scale);
        rv.z = __expf(acc[i][2] * scale);
        rv.w = __expf(acc[i][3] * scale);
        *reinterpret_cast<float4*>(&rbf_s[4 * tr + i][4 * tc]) = rv;
    }
    __syncthreads();

    // ---- epilogue: out[row][o] partial over this block's 128 h
    {
        const int row = tid >> 3;   // 0..31
        const int sl  = tid & 7;    // 0..7, 16 h each
        float po[Odim];
#pragma unroll
        for (int o = 0; o < Odim; ++o) po[o] = 0.0f;

#pragma unroll
        for (int k4 = 0; k4 < 4; ++k4) {
            int hh = sl * 16 + k4 * 4;
            float4 rv = *reinterpret_cast<const float4*>(&rbf_s[row][hh]);
#pragma unroll
            for (int o = 0; o < Odim; ++o) {
                float4 wv = *reinterpret_cast<const float4*>(&W_s[o][hh]);
                po[o] = fmaf(rv.x, wv.x, po[o]);
                po[o] = fmaf(rv.y, wv.y, po[o]);
                po[o] = fmaf(rv.z, wv.z, po[o]);
                po[o] = fmaf(rv.w, wv.w, po[o]);
            }
        }
        // reduce over sl (lane bits 0..2, within wave)
#pragma unroll
        for (int s = 1; s < 8; s <<= 1) {
#pragma unroll
            for (int o = 0; o < Odim; ++o)
                po[o] += __shfl_xor(po[o], s, 64);
        }
        if (sl == 0) {
#pragma unroll
            for (int o = 0; o < Odim; ++o) {
                float v = po[o];
                if (blockIdx.y == 0) v += bias[o];
                atomicAdd(&out[(size_t)(row0 + row) * Odim + o], v);
            }
        }
    }
}

extern "C" void kernel_launch(void* const* d_in, const int* in_sizes, int n_in,
                              void* d_out, int out_size, void* d_ws, size_t ws_size,
                              hipStream_t stream) {
    const float* x  = (const float*)d_in[0];
    const float* c  = (const float*)d_in[1];
    const float* sg = (const float*)d_in[2];
    const float* W  = (const float*)d_in[3];
    const float* b  = (const float*)d_in[4];
    float* out      = (float*)d_out;

    const int B = in_sizes[0] / Fdim;   // 2048

    // zero output (atomicAdd accumulation; harness poisons d_out before timing)
    hipMemsetAsync(d_out, 0, (size_t)out_size * sizeof(float), stream);

    dim3 grid(B / BM, Hdim / BH);
    rbf_fused<<<grid, 256, 0, stream>>>(x, c, sg, W, b, out);
}

// Round 2
// 22.708 us; speedup vs baseline: 1.0064x; 1.0064x over previous
//
#include <hip/hip_runtime.h>

// RBF network fused kernel, fp32 vector path, GEMM-form distances.
// inputs:  x[B=2048][F=128], centers c[H=512][F=128], sigma[1], W[O=10][H=512], b[O=10]
// out[b][o] = sum_h exp(-||x_b - c_h||^2 / (2 sigma^2)) * W[o][h] + b[o]
// dist = |x|^2 + |c|^2 - 2 x.c   (norms computed during staging, dot via LDS-tiled FMA loop)

constexpr int Fdim = 128;
constexpr int Hdim = 512;
constexpr int Odim = 10;
constexpr int BM   = 16;    // rows per block
constexpr int BH   = 128;   // centers per block
constexpr int KC   = 64;    // F chunk staged in LDS
constexpr int LDC  = 130;   // cT row stride (pad: 4-way staging-write conflict, conflict-free b64 reads)
constexpr int LDX  = 20;    // xT row stride (16B-aligned b128 rows)

__global__ __launch_bounds__(256, 2) void rbf_fused(
    const float* __restrict__ x,
    const float* __restrict__ c,
    const float* __restrict__ sigmap,
    const float* __restrict__ W,
    const float* __restrict__ bias,
    float* __restrict__ out)
{
    __shared__ float cT[KC][LDC];        // 33.3 KB  cT[f][h]
    __shared__ float xT[KC][LDX];        //  5.1 KB  xT[f][r]
    __shared__ float W_s[Odim][BH];      //  5.1 KB
    __shared__ float rbf_s[BM][BH + 4];  //  8.4 KB
    __shared__ float xn_s[BM];
    __shared__ float cn_s[BH];           // total ~51.3 KB -> LDS allows 3 blocks/CU

    const int tid  = threadIdx.x;
    const int lane = tid & 63;
    const int w    = tid >> 6;          // wave 0..3 -> rows 4w..4w+3
    const int row0 = blockIdx.x * BM;
    const int h0   = blockIdx.y * BH;

    // ---- stage W tile (once)
#pragma unroll
    for (int k = 0; k < (Odim * BH) / 256; ++k) {   // 5
        int idx = tid + 256 * k;
        W_s[idx >> 7][idx & 127] = W[(idx >> 7) * Hdim + h0 + (idx & 127)];
    }

    const int f4 = tid & 15;    // f-quad within chunk
    const int rr = tid >> 4;    // 0..15

    float xn_part = 0.0f;
    float cn_part[8];
#pragma unroll
    for (int p = 0; p < 8; ++p) cn_part[p] = 0.0f;

    float acc[4][2];
#pragma unroll
    for (int i = 0; i < 4; ++i) { acc[i][0] = 0.0f; acc[i][1] = 0.0f; }

    const float4* x4 = reinterpret_cast<const float4*>(x);
    const float4* c4 = reinterpret_cast<const float4*>(c);

    for (int fc = 0; fc < Fdim; fc += KC) {
        // ---- stage x chunk: xT[floc][r], plus row-norm partial (squares while in regs)
        {
            float4 v = x4[(size_t)(row0 + rr) * (Fdim / 4) + fc / 4 + f4];
            xT[4 * f4 + 0][rr] = v.x;
            xT[4 * f4 + 1][rr] = v.y;
            xT[4 * f4 + 2][rr] = v.z;
            xT[4 * f4 + 3][rr] = v.w;
            float s = v.x * v.x + v.y * v.y + v.z * v.z + v.w * v.w;
#pragma unroll
            for (int sft = 1; sft < 16; sft <<= 1) s += __shfl_xor(s, sft, 64);
            xn_part += s;   // all 16 lanes of this r-group hold the chunk sum
        }
        // ---- stage c chunk: cT[floc][h], plus center-norm partials
#pragma unroll
        for (int p = 0; p < 8; ++p) {
            int hh = rr + 16 * p;
            float4 v = c4[(size_t)(h0 + hh) * (Fdim / 4) + fc / 4 + f4];
            cT[4 * f4 + 0][hh] = v.x;
            cT[4 * f4 + 1][hh] = v.y;
            cT[4 * f4 + 2][hh] = v.z;
            cT[4 * f4 + 3][hh] = v.w;
            float s = v.x * v.x + v.y * v.y + v.z * v.z + v.w * v.w;
#pragma unroll
            for (int sft = 1; sft < 16; sft <<= 1) s += __shfl_xor(s, sft, 64);
            cn_part[p] += s;
        }
        __syncthreads();

        // ---- main loop: wave w owns rows 4w..4w+3, lane owns cols 2*lane..2*lane+1
        // x read is wave-uniform (LDS broadcast, free); c read contiguous b64 (conflict-free)
#pragma unroll 8
        for (int f = 0; f < KC; ++f) {
            float4 xv = *reinterpret_cast<const float4*>(&xT[f][4 * w]);
            float2 cv = *reinterpret_cast<const float2*>(&cT[f][2 * lane]);
            acc[0][0] = fmaf(xv.x, cv.x, acc[0][0]);
            acc[0][1] = fmaf(xv.x, cv.y, acc[0][1]);
            acc[1][0] = fmaf(xv.y, cv.x, acc[1][0]);
            acc[1][1] = fmaf(xv.y, cv.y, acc[1][1]);
            acc[2][0] = fmaf(xv.z, cv.x, acc[2][0]);
            acc[2][1] = fmaf(xv.z, cv.y, acc[2][1]);
            acc[3][0] = fmaf(xv.w, cv.x, acc[3][0]);
            acc[3][1] = fmaf(xv.w, cv.y, acc[3][1]);
        }
        __syncthreads();
    }

    // ---- publish norms
    if (f4 == 0) {
        xn_s[rr] = xn_part;
#pragma unroll
        for (int p = 0; p < 8; ++p) cn_s[rr + 16 * p] = cn_part[p];
    }
    __syncthreads();

    // ---- rbf = exp(dist * scale), dist = xn + cn - 2*dot
    const float sg    = sigmap[0];
    const float scale = -1.0f / (2.0f * sg * sg);
    {
        float2 cn = *reinterpret_cast<const float2*>(&cn_s[2 * lane]);
#pragma unroll
        for (int i = 0; i < 4; ++i) {
            float xn = xn_s[4 * w + i];
            float d0 = xn + cn.x - 2.0f * acc[i][0];
            float d1 = xn + cn.y - 2.0f * acc[i][1];
            float2 rv;
            rv.x = __expf(d0 * scale);
            rv.y = __expf(d1 * scale);
            *reinterpret_cast<float2*>(&rbf_s[4 * w + i][2 * lane]) = rv;
        }
    }
    __syncthreads();

    // ---- epilogue: out[row][o] partial over this block's 128 h
    {
        const int row = tid >> 4;   // 0..15
        const int sl  = tid & 15;   // 16 slices of 8 h
        float po[Odim];
#pragma unroll
        for (int o = 0; o < Odim; ++o) po[o] = 0.0f;

#pragma unroll
        for (int k4 = 0; k4 < 2; ++k4) {
            int hh = sl * 8 + k4 * 4;
            float4 rv = *reinterpret_cast<const float4*>(&rbf_s[row][hh]);
#pragma unroll
            for (int o = 0; o < Odim; ++o) {
                float4 wv = *reinterpret_cast<const float4*>(&W_s[o][hh]);
                po[o] = fmaf(rv.x, wv.x, po[o]);
                po[o] = fmaf(rv.y, wv.y, po[o]);
                po[o] = fmaf(rv.z, wv.z, po[o]);
                po[o] = fmaf(rv.w, wv.w, po[o]);
            }
        }
#pragma unroll
        for (int s = 1; s < 16; s <<= 1) {
#pragma unroll
            for (int o = 0; o < Odim; ++o)
                po[o] += __shfl_xor(po[o], s, 64);
        }
        if (sl == 0) {
#pragma unroll
            for (int o = 0; o < Odim; ++o) {
                float v = po[o];
                if (blockIdx.y == 0) v += bias[o];
                atomicAdd(&out[(size_t)(row0 + row) * Odim + o], v);
            }
        }
    }
}

extern "C" void kernel_launch(void* const* d_in, const int* in_sizes, int n_in,
                              void* d_out, int out_size, void* d_ws, size_t ws_size,
                              hipStream_t stream) {
    const float* x  = (const float*)d_in[0];
    const float* c  = (const float*)d_in[1];
    const float* sg = (const float*)d_in[2];
    const float* W  = (const float*)d_in[3];
    const float* b  = (const float*)d_in[4];
    float* out      = (float*)d_out;

    const int B = in_sizes[0] / Fdim;   // 2048

    // zero output (atomicAdd accumulation; harness does not re-zero between replays)
    hipMemsetAsync(d_out, 0, (size_t)out_size * sizeof(float), stream);

    dim3 grid(B / BM, Hdim / BH);
    rbf_fused<<<grid, 256, 0, stream>>>(x, c, sg, W, b, out);
}

// Round 3
// 19.756 us; speedup vs baseline: 1.1567x; 1.1494x over previous
//
#include <hip/hip_runtime.h>

// RBF network, fp32, GEMM-form distances, split-H two-kernel scheme (no memset, no atomics).
// inputs:  x[B=2048][F=128], centers c[H=512][F=128], sigma[1], W[O=10][H=512], b[O=10]
// k1: partial[by][b][o] = sum_{h in slice by} exp(-||x_b-c_h||^2/(2 s^2)) * W[o][h]
// k2: out[b][o] = bias[o] + sum_by partial[by][b][o]

constexpr int Fdim = 128;
constexpr int Hdim = 512;
constexpr int Odim = 10;
constexpr int BM   = 16;    // rows per block
constexpr int BH   = 128;   // centers per block
constexpr int KC   = 64;    // F chunk staged in LDS
constexpr int LDC  = 130;   // cT row stride
constexpr int LDX  = 20;    // xT row stride

__global__ __launch_bounds__(256, 2) void rbf_partial(
    const float* __restrict__ x,
    const float* __restrict__ c,
    const float* __restrict__ sigmap,
    const float* __restrict__ W,
    float* __restrict__ ws)          // [Hdim/BH][B][Odim]
{
    __shared__ float cT[KC][LDC];
    __shared__ float xT[KC][LDX];
    __shared__ float W_s[Odim][BH];
    __shared__ float rbf_s[BM][BH + 4];
    __shared__ float xn_s[BM];
    __shared__ float cn_s[BH];

    const int tid  = threadIdx.x;
    const int lane = tid & 63;
    const int w    = tid >> 6;
    const int row0 = blockIdx.x * BM;
    const int h0   = blockIdx.y * BH;

#pragma unroll
    for (int k = 0; k < (Odim * BH) / 256; ++k) {
        int idx = tid + 256 * k;
        W_s[idx >> 7][idx & 127] = W[(idx >> 7) * Hdim + h0 + (idx & 127)];
    }

    const int f4 = tid & 15;
    const int rr = tid >> 4;

    float xn_part = 0.0f;
    float cn_part[8];
#pragma unroll
    for (int p = 0; p < 8; ++p) cn_part[p] = 0.0f;

    float acc[4][2];
#pragma unroll
    for (int i = 0; i < 4; ++i) { acc[i][0] = 0.0f; acc[i][1] = 0.0f; }

    const float4* x4 = reinterpret_cast<const float4*>(x);
    const float4* c4 = reinterpret_cast<const float4*>(c);

    for (int fc = 0; fc < Fdim; fc += KC) {
        {
            float4 v = x4[(size_t)(row0 + rr) * (Fdim / 4) + fc / 4 + f4];
            xT[4 * f4 + 0][rr] = v.x;
            xT[4 * f4 + 1][rr] = v.y;
            xT[4 * f4 + 2][rr] = v.z;
            xT[4 * f4 + 3][rr] = v.w;
            float s = v.x * v.x + v.y * v.y + v.z * v.z + v.w * v.w;
#pragma unroll
            for (int sft = 1; sft < 16; sft <<= 1) s += __shfl_xor(s, sft, 64);
            xn_part += s;
        }
#pragma unroll
        for (int p = 0; p < 8; ++p) {
            int hh = rr + 16 * p;
            float4 v = c4[(size_t)(h0 + hh) * (Fdim / 4) + fc / 4 + f4];
            cT[4 * f4 + 0][hh] = v.x;
            cT[4 * f4 + 1][hh] = v.y;
            cT[4 * f4 + 2][hh] = v.z;
            cT[4 * f4 + 3][hh] = v.w;
            float s = v.x * v.x + v.y * v.y + v.z * v.z + v.w * v.w;
#pragma unroll
            for (int sft = 1; sft < 16; sft <<= 1) s += __shfl_xor(s, sft, 64);
            cn_part[p] += s;
        }
        __syncthreads();

#pragma unroll 8
        for (int f = 0; f < KC; ++f) {
            float4 xv = *reinterpret_cast<const float4*>(&xT[f][4 * w]);
            float2 cv = *reinterpret_cast<const float2*>(&cT[f][2 * lane]);
            acc[0][0] = fmaf(xv.x, cv.x, acc[0][0]);
            acc[0][1] = fmaf(xv.x, cv.y, acc[0][1]);
            acc[1][0] = fmaf(xv.y, cv.x, acc[1][0]);
            acc[1][1] = fmaf(xv.y, cv.y, acc[1][1]);
            acc[2][0] = fmaf(xv.z, cv.x, acc[2][0]);
            acc[2][1] = fmaf(xv.z, cv.y, acc[2][1]);
            acc[3][0] = fmaf(xv.w, cv.x, acc[3][0]);
            acc[3][1] = fmaf(xv.w, cv.y, acc[3][1]);
        }
        __syncthreads();
    }

    if (f4 == 0) {
        xn_s[rr] = xn_part;
#pragma unroll
        for (int p = 0; p < 8; ++p) cn_s[rr + 16 * p] = cn_part[p];
    }
    __syncthreads();

    const float sg    = sigmap[0];
    const float scale = -1.0f / (2.0f * sg * sg);
    {
        float2 cn = *reinterpret_cast<const float2*>(&cn_s[2 * lane]);
#pragma unroll
        for (int i = 0; i < 4; ++i) {
            float xn = xn_s[4 * w + i];
            float d0 = xn + cn.x - 2.0f * acc[i][0];
            float d1 = xn + cn.y - 2.0f * acc[i][1];
            float2 rv;
            rv.x = __expf(d0 * scale);
            rv.y = __expf(d1 * scale);
            *reinterpret_cast<float2*>(&rbf_s[4 * w + i][2 * lane]) = rv;
        }
    }
    __syncthreads();

    {
        const int row = tid >> 4;
        const int sl  = tid & 15;
        float po[Odim];
#pragma unroll
        for (int o = 0; o < Odim; ++o) po[o] = 0.0f;

#pragma unroll
        for (int k4 = 0; k4 < 2; ++k4) {
            int hh = sl * 8 + k4 * 4;
            float4 rv = *reinterpret_cast<const float4*>(&rbf_s[row][hh]);
#pragma unroll
            for (int o = 0; o < Odim; ++o) {
                float4 wv = *reinterpret_cast<const float4*>(&W_s[o][hh]);
                po[o] = fmaf(rv.x, wv.x, po[o]);
                po[o] = fmaf(rv.y, wv.y, po[o]);
                po[o] = fmaf(rv.z, wv.z, po[o]);
                po[o] = fmaf(rv.w, wv.w, po[o]);
            }
        }
#pragma unroll
        for (int s = 1; s < 16; s <<= 1) {
#pragma unroll
            for (int o = 0; o < Odim; ++o)
                po[o] += __shfl_xor(po[o], s, 64);
        }
        if (sl == 0) {
            float* pw = ws + ((size_t)blockIdx.y * gridDim.x * BM + row0 + row) * Odim;
#pragma unroll
            for (int o = 0; o < Odim; ++o) pw[o] = po[o];
        }
    }
}

__global__ __launch_bounds__(256) void reduce4(
    const float* __restrict__ ws,    // [4][B][Odim]
    const float* __restrict__ bias,
    float* __restrict__ out,
    int n)                           // B*Odim
{
    int idx = blockIdx.x * 256 + threadIdx.x;
    if (idx < n) {
        int o = idx % Odim;
        float v = bias[o];
        v += ws[idx];
        v += ws[n + idx];
        v += ws[2 * n + idx];
        v += ws[3 * n + idx];
        out[idx] = v;
    }
}

extern "C" void kernel_launch(void* const* d_in, const int* in_sizes, int n_in,
                              void* d_out, int out_size, void* d_ws, size_t ws_size,
                              hipStream_t stream) {
    const float* x  = (const float*)d_in[0];
    const float* c  = (const float*)d_in[1];
    const float* sg = (const float*)d_in[2];
    const float* W  = (const float*)d_in[3];
    const float* b  = (const float*)d_in[4];
    float* out      = (float*)d_out;
    float* ws       = (float*)d_ws;

    const int B = in_sizes[0] / Fdim;   // 2048

    dim3 grid(B / BM, Hdim / BH);
    rbf_partial<<<grid, 256, 0, stream>>>(x, c, sg, W, ws);

    const int n = B * Odim;             // 20480
    reduce4<<<(n + 255) / 256, 256, 0, stream>>>(ws, b, out, n);
}

// Round 4
// 18.669 us; speedup vs baseline: 1.2241x; 1.0583x over previous
//
#include <hip/hip_runtime.h>

// RBF network, single fused kernel (one graph node, no scratch, no atomics).
// inputs:  x[B=2048][F=128], centers c[H=512][F=128], sigma[1], W[O=10][H=512], b[O=10]
// Each block: 8 rows x ALL 512 centers -> h-reduction is block-local, plain store.
// dist = |x|^2 + |c|^2 - 2 x.c ; norms computed during staging.

constexpr int Fdim = 128;
constexpr int Hdim = 512;
constexpr int Odim = 10;
constexpr int BM   = 8;     // rows per block
constexpr int KC   = 32;    // F chunk staged in LDS
constexpr int LDC  = 514;   // cT row stride (2-way-free writes, conflict-free b64 reads)
constexpr int LDX  = 12;    // xT row stride (16B-aligned rows)
constexpr int LDR  = 516;   // rbf_s row stride

__global__ __launch_bounds__(512, 1) void rbf_all(
    const float* __restrict__ x,
    const float* __restrict__ c,
    const float* __restrict__ sigmap,
    const float* __restrict__ W,
    const float* __restrict__ bias,
    float* __restrict__ out)
{
    __shared__ float cT[KC][LDC];        // 65.8 KB  cT[f][h], all 512 h
    __shared__ float xT[KC][LDX];        //  1.5 KB
    __shared__ float W_s[Odim][Hdim];    // 20.5 KB
    __shared__ float rbf_s[BM][LDR];     // 16.5 KB
    __shared__ float xn_s[BM];
    __shared__ float cn_s[Hdim];         // total ~104 KB -> 1 block/CU

    const int tid  = threadIdx.x;
    const int lane = tid & 63;
    const int wave = tid >> 6;          // 0..7
    const int wr   = wave >> 2;         // row-group 0..1 -> rows 4wr..4wr+3
    const int wh   = wave & 3;          // h-group: h in [wh*128, wh*128+128)
    const int row0 = blockIdx.x * BM;

    // ---- stage W (once): flat copy, W_s[o][h] <- W[o*512+h]
#pragma unroll
    for (int k = 0; k < (Odim * Hdim) / 512; ++k) {   // 10
        int idx = tid + 512 * k;
        W_s[idx >> 9][idx & 511] = W[idx];
    }

    const int f4 = tid & 7;     // f-quad within chunk (8 quads = 32 f)
    const int hh = tid >> 3;    // 0..63

    float cn_part[8];
#pragma unroll
    for (int p = 0; p < 8; ++p) cn_part[p] = 0.0f;
    float xn_part = 0.0f;

    float acc[4][2];
#pragma unroll
    for (int i = 0; i < 4; ++i) { acc[i][0] = 0.0f; acc[i][1] = 0.0f; }

    const float4* x4 = reinterpret_cast<const float4*>(x);
    const float4* c4 = reinterpret_cast<const float4*>(c);

    for (int fc = 0; fc < Fdim; fc += KC) {
        // ---- stage x chunk (wave 0 only): xT[floc][r] + row-norm partials
        if (tid < 64) {
            float4 v = x4[(size_t)(row0 + hh) * (Fdim / 4) + fc / 4 + f4];
            xT[4 * f4 + 0][hh] = v.x;
            xT[4 * f4 + 1][hh] = v.y;
            xT[4 * f4 + 2][hh] = v.z;
            xT[4 * f4 + 3][hh] = v.w;
            float s = v.x * v.x + v.y * v.y + v.z * v.z + v.w * v.w;
            s += __shfl_xor(s, 1, 64);
            s += __shfl_xor(s, 2, 64);
            s += __shfl_xor(s, 4, 64);
            xn_part += s;
        }
        // ---- stage c chunk: cT[floc][h] (all 512 h) + center-norm partials
#pragma unroll
        for (int p = 0; p < 8; ++p) {
            int h = hh + 64 * p;
            float4 v = c4[(size_t)h * (Fdim / 4) + fc / 4 + f4];
            cT[4 * f4 + 0][h] = v.x;
            cT[4 * f4 + 1][h] = v.y;
            cT[4 * f4 + 2][h] = v.z;
            cT[4 * f4 + 3][h] = v.w;
            float s = v.x * v.x + v.y * v.y + v.z * v.z + v.w * v.w;
            s += __shfl_xor(s, 1, 64);
            s += __shfl_xor(s, 2, 64);
            s += __shfl_xor(s, 4, 64);
            cn_part[p] += s;
        }
        __syncthreads();

        // ---- main loop: wave (wr,wh) owns rows 4wr..4wr+3 x cols wh*128+2*lane..+1
        // x read wave-uniform (broadcast, free); c read contiguous b64 (2-way, free)
#pragma unroll 8
        for (int f = 0; f < KC; ++f) {
            float4 xv = *reinterpret_cast<const float4*>(&xT[f][4 * wr]);
            float2 cv = *reinterpret_cast<const float2*>(&cT[f][wh * 128 + 2 * lane]);
            acc[0][0] = fmaf(xv.x, cv.x, acc[0][0]);
            acc[0][1] = fmaf(xv.x, cv.y, acc[0][1]);
            acc[1][0] = fmaf(xv.y, cv.x, acc[1][0]);
            acc[1][1] = fmaf(xv.y, cv.y, acc[1][1]);
            acc[2][0] = fmaf(xv.z, cv.x, acc[2][0]);
            acc[2][1] = fmaf(xv.z, cv.y, acc[2][1]);
            acc[3][0] = fmaf(xv.w, cv.x, acc[3][0]);
            acc[3][1] = fmaf(xv.w, cv.y, acc[3][1]);
        }
        __syncthreads();
    }

    // ---- publish norms
    if (f4 == 0) {
#pragma unroll
        for (int p = 0; p < 8; ++p) cn_s[hh + 64 * p] = cn_part[p];
        if (tid < 64) xn_s[hh] = xn_part;
    }
    __syncthreads();

    // ---- rbf = exp(dist*scale) -> rbf_s
    const float sg    = sigmap[0];
    const float scale = -1.0f / (2.0f * sg * sg);
    {
        float2 cn = *reinterpret_cast<const float2*>(&cn_s[wh * 128 + 2 * lane]);
#pragma unroll
        for (int i = 0; i < 4; ++i) {
            float xn = xn_s[4 * wr + i];
            float2 rv;
            rv.x = __expf((xn + cn.x - 2.0f * acc[i][0]) * scale);
            rv.y = __expf((xn + cn.y - 2.0f * acc[i][1]) * scale);
            *reinterpret_cast<float2*>(&rbf_s[4 * wr + i][wh * 128 + 2 * lane]) = rv;
        }
    }
    __syncthreads();

    // ---- GEMV epilogue: wave = row, lane h-mapping CONTIGUOUS (conflict-free b32)
    {
        const int row = wave;   // 0..7
        float po[Odim];
#pragma unroll
        for (int o = 0; o < Odim; ++o) po[o] = 0.0f;

#pragma unroll
        for (int k = 0; k < 8; ++k) {
            int h = lane + 64 * k;
            float r = rbf_s[row][h];
#pragma unroll
            for (int o = 0; o < Odim; ++o)
                po[o] = fmaf(r, W_s[o][h], po[o]);
        }
#pragma unroll
        for (int s = 1; s < 64; s <<= 1) {
#pragma unroll
            for (int o = 0; o < Odim; ++o)
                po[o] += __shfl_xor(po[o], s, 64);
        }
        if (lane == 0) {
#pragma unroll
            for (int o = 0; o < Odim; ++o)
                out[(size_t)(row0 + row) * Odim + o] = po[o] + bias[o];
        }
    }
}

extern "C" void kernel_launch(void* const* d_in, const int* in_sizes, int n_in,
                              void* d_out, int out_size, void* d_ws, size_t ws_size,
                              hipStream_t stream) {
    const float* x  = (const float*)d_in[0];
    const float* c  = (const float*)d_in[1];
    const float* sg = (const float*)d_in[2];
    const float* W  = (const float*)d_in[3];
    const float* b  = (const float*)d_in[4];
    float* out      = (float*)d_out;

    const int B = in_sizes[0] / Fdim;   // 2048

    rbf_all<<<B / BM, 512, 0, stream>>>(x, c, sg, W, b, out);
}

// Round 5
// 17.641 us; speedup vs baseline: 1.2954x; 1.0582x over previous
//
#include <hip/hip_runtime.h>

// RBF network, single fused kernel, reg-prefetch double-buffered c staging (T14).
// inputs:  x[B=2048][F=128], centers c[H=512][F=128], sigma[1], W[O=10][H=512], b[O=10]
// Each block: 8 rows x ALL 512 centers; dist = |x|^2+|c|^2-2x.c; plain store, no atomics.

constexpr int Fdim = 128;
constexpr int Hdim = 512;
constexpr int Odim = 10;
constexpr int BM   = 8;     // rows per block
constexpr int KC   = 32;    // F chunk resident in LDS
constexpr int NCH  = Fdim / KC;   // 4
constexpr int LDC  = 513;   // cT row stride (2-way-free writes, conflict-free b64 reads)
constexpr int LDXT = 12;    // xT row stride (48B rows, b128-aligned at 4*wr)
constexpr int LDR  = 516;   // rbf_s row stride

__global__ __launch_bounds__(512, 1) void rbf_all(
    const float* __restrict__ x,
    const float* __restrict__ c,
    const float* __restrict__ sigmap,
    const float* __restrict__ W,
    const float* __restrict__ bias,
    float* __restrict__ out)
{
    __shared__ float cT[KC][LDC];        // 65.7 KB  current c chunk, f-major
    __shared__ float xT[Fdim][LDXT];     //  6.1 KB  all x rows, f-major (staged once)
    __shared__ float W_s[Odim][Hdim];    // 20.5 KB
    __shared__ float rbf_s[BM][LDR];     // 16.5 KB
    __shared__ float xn_s[BM];
    __shared__ float cn_s[Hdim];         // total ~111 KB -> 1 block/CU (grid=256 anyway)

    const int tid  = threadIdx.x;
    const int lane = tid & 63;
    const int wave = tid >> 6;          // 0..7
    const int wr   = wave >> 2;         // rows 4wr..4wr+3
    const int wh   = wave & 3;          // h in [wh*128, wh*128+128)
    const int row0 = blockIdx.x * BM;

    const float4* x4 = reinterpret_cast<const float4*>(x);
    const float4* c4 = reinterpret_cast<const float4*>(c);

    // ---- stage W (once): flat copy
#pragma unroll
    for (int k = 0; k < (Odim * Hdim) / 512; ++k) {   // 10
        int idx = tid + 512 * k;
        W_s[idx >> 9][idx & 511] = W[idx];
    }

    // ---- stage ALL x, transposed (once), + row norms
    if (tid < 256) {
        int r  = tid >> 5;    // 0..7
        int fq = tid & 31;    // float4 index along f
        float4 v = x4[(size_t)(row0 + r) * (Fdim / 4) + fq];
        xT[4 * fq + 0][r] = v.x;
        xT[4 * fq + 1][r] = v.y;
        xT[4 * fq + 2][r] = v.z;
        xT[4 * fq + 3][r] = v.w;
        float s = v.x * v.x + v.y * v.y + v.z * v.z + v.w * v.w;
#pragma unroll
        for (int sft = 1; sft < 32; sft <<= 1) s += __shfl_xor(s, sft, 64);
        if (fq == 0) xn_s[r] = s;
    }

    // ---- c staging: reg-prefetch double buffer
    const int f4 = tid & 7;     // f-quad within chunk
    const int hh = tid >> 3;    // 0..63

    float4 pre[8];
    float cn_part[8];
#pragma unroll
    for (int p = 0; p < 8; ++p) cn_part[p] = 0.0f;

    // prologue: load chunk 0 into regs, write to LDS
#pragma unroll
    for (int p = 0; p < 8; ++p)
        pre[p] = c4[(size_t)(hh + 64 * p) * (Fdim / 4) + f4];
#pragma unroll
    for (int p = 0; p < 8; ++p) {
        float4 v = pre[p];
        int h = hh + 64 * p;
        cT[4 * f4 + 0][h] = v.x;
        cT[4 * f4 + 1][h] = v.y;
        cT[4 * f4 + 2][h] = v.z;
        cT[4 * f4 + 3][h] = v.w;
        cn_part[p] += v.x * v.x + v.y * v.y + v.z * v.z + v.w * v.w;
    }
    __syncthreads();   // cT chunk0 + xT + W_s visible

    float acc[4][2];
#pragma unroll
    for (int i = 0; i < 4; ++i) { acc[i][0] = 0.0f; acc[i][1] = 0.0f; }

    for (int k = 0; k < NCH; ++k) {
        // issue next chunk's global loads (latency hides under compute below)
        if (k + 1 < NCH) {
#pragma unroll
            for (int p = 0; p < 8; ++p)
                pre[p] = c4[(size_t)(hh + 64 * p) * (Fdim / 4) + (k + 1) * (KC / 4) + f4];
        }

        // ---- compute chunk k: x read wave-uniform b128 (broadcast), c read b64 contiguous
#pragma unroll 8
        for (int f = 0; f < KC; ++f) {
            float4 xv = *reinterpret_cast<const float4*>(&xT[k * KC + f][4 * wr]);
            float2 cv = *reinterpret_cast<const float2*>(&cT[f][wh * 128 + 2 * lane]);
            acc[0][0] = fmaf(xv.x, cv.x, acc[0][0]);
            acc[0][1] = fmaf(xv.x, cv.y, acc[0][1]);
            acc[1][0] = fmaf(xv.y, cv.x, acc[1][0]);
            acc[1][1] = fmaf(xv.y, cv.y, acc[1][1]);
            acc[2][0] = fmaf(xv.z, cv.x, acc[2][0]);
            acc[2][1] = fmaf(xv.z, cv.y, acc[2][1]);
            acc[3][0] = fmaf(xv.w, cv.x, acc[3][0]);
            acc[3][1] = fmaf(xv.w, cv.y, acc[3][1]);
        }

        if (k + 1 < NCH) {
            __syncthreads();   // everyone done reading cT chunk k
#pragma unroll
            for (int p = 0; p < 8; ++p) {
                float4 v = pre[p];
                int h = hh + 64 * p;
                cT[4 * f4 + 0][h] = v.x;
                cT[4 * f4 + 1][h] = v.y;
                cT[4 * f4 + 2][h] = v.z;
                cT[4 * f4 + 3][h] = v.w;
                cn_part[p] += v.x * v.x + v.y * v.y + v.z * v.z + v.w * v.w;
            }
            __syncthreads();   // chunk k+1 visible
        }
    }

    // ---- publish center norms (reduce over the 8 f4-lanes)
#pragma unroll
    for (int p = 0; p < 8; ++p) {
        float s = cn_part[p];
        s += __shfl_xor(s, 1, 64);
        s += __shfl_xor(s, 2, 64);
        s += __shfl_xor(s, 4, 64);
        cn_part[p] = s;
    }
    if (f4 == 0) {
#pragma unroll
        for (int p = 0; p < 8; ++p) cn_s[hh + 64 * p] = cn_part[p];
    }
    __syncthreads();

    // ---- rbf = exp(dist*scale) -> rbf_s
    const float sg    = sigmap[0];
    const float scale = -1.0f / (2.0f * sg * sg);
    {
        float2 cn = *reinterpret_cast<const float2*>(&cn_s[wh * 128 + 2 * lane]);
#pragma unroll
        for (int i = 0; i < 4; ++i) {
            float xn = xn_s[4 * wr + i];
            float2 rv;
            rv.x = __expf((xn + cn.x - 2.0f * acc[i][0]) * scale);
            rv.y = __expf((xn + cn.y - 2.0f * acc[i][1]) * scale);
            *reinterpret_cast<float2*>(&rbf_s[4 * wr + i][wh * 128 + 2 * lane]) = rv;
        }
    }
    __syncthreads();

    // ---- GEMV epilogue: wave = row, lane h-mapping contiguous (conflict-free)
    {
        const int row = wave;   // 0..7
        float po[Odim];
#pragma unroll
        for (int o = 0; o < Odim; ++o) po[o] = 0.0f;

#pragma unroll
        for (int k = 0; k < 8; ++k) {
            int h = lane + 64 * k;
            float r = rbf_s[row][h];
#pragma unroll
            for (int o = 0; o < Odim; ++o)
                po[o] = fmaf(r, W_s[o][h], po[o]);
        }
#pragma unroll
        for (int s = 1; s < 64; s <<= 1) {
#pragma unroll
            for (int o = 0; o < Odim; ++o)
                po[o] += __shfl_xor(po[o], s, 64);
        }
        if (lane == 0) {
#pragma unroll
            for (int o = 0; o < Odim; ++o)
                out[(size_t)(row0 + row) * Odim + o] = po[o] + bias[o];
        }
    }
}

extern "C" void kernel_launch(void* const* d_in, const int* in_sizes, int n_in,
                              void* d_out, int out_size, void* d_ws, size_t ws_size,
                              hipStream_t stream) {
    const float* x  = (const float*)d_in[0];
    const float* c  = (const float*)d_in[1];
    const float* sg = (const float*)d_in[2];
    const float* W  = (const float*)d_in[3];
    const float* b  = (const float*)d_in[4];
    float* out      = (float*)d_out;

    const int B = in_sizes[0] / Fdim;   // 2048

    rbf_all<<<B / BM, 512, 0, stream>>>(x, c, sg, W, b, out);
}